// Round 9
// baseline (285.841 us; speedup 1.0000x reference)
//
#include <hip/hip_runtime.h>

#define NN 50000   // nodes
#define NE 600000  // edges
#define DF 128     // features
#define NB 16384   // pair batch
#define SCA_B 128                 // pass-A blocks
#define SCA_PER ((NE + SCA_B - 1) / SCA_B)   // 4688 edges/block
#define SCB_CAP 4352              // pass-B LDS edge capacity (23 sigma)

typedef short bf16x8 __attribute__((ext_vector_type(8)));
typedef float f32x4 __attribute__((ext_vector_type(4)));

__device__ __forceinline__ float bf2f(unsigned short u){
  return __uint_as_float(((unsigned int)u) << 16);
}
__device__ __forceinline__ unsigned short f2bf(float x){
  unsigned int b = __float_as_uint(x);
  return (unsigned short)((b + 0x7FFFu + ((b >> 16) & 1u)) >> 16);
}

// Original template symbol (defined, never launched).
__global__ void GraphSAGE_8504035246140_kernel(){ }

// ---- fused prelude: h cast | zero cnt/fill | zero stats | weight swizzle ----
__global__ __launch_bounds__(256) void k_prelude(
    const float* h_in, unsigned short* h_c,
    const float* Ws, const float* Wn, const float* W1,
    unsigned short* WsB, unsigned short* WnB, unsigned short* W1B,
    int* cnt, float* stats){
  int b = blockIdx.x, t = threadIdx.x;
  if (b < 3125){                       // 3125*256 == NN*DF/8 exactly
    int i = b * 256 + t;
    const float4* s = (const float4*)h_in;
    float4 v0 = s[i * 2], v1 = s[i * 2 + 1];
    unsigned short d[8] = {f2bf(v0.x), f2bf(v0.y), f2bf(v0.z), f2bf(v0.w),
                           f2bf(v1.x), f2bf(v1.y), f2bf(v1.z), f2bf(v1.w)};
    *(bf16x8*)(h_c + i * 8) = *(bf16x8*)d;
  } else if (b < 3516){
    int i = (b - 3125) * 256 + t;
    if (i < 2 * NN) cnt[i] = 0;        // cnt + fill (adjacent)
  } else if (b < 3518){
    int i = (b - 3516) * 256 + t;
    if (i < 512) stats[i] = 0.f;
  } else {
    int idx = (b - 3518) * 256 + t;    // 192 blocks -> 49152 threads
    if (idx < 2 * DF * DF){
      int layer = idx >> 14;
      int e = idx & (DF * DF - 1);
      int k = e >> 7, n = e & 127;
      int dst = layer * DF * DF + (((k >> 3) * 128 + n) << 3) + (k & 7);
      WsB[dst] = f2bf(Ws[idx]);
      WnB[dst] = f2bf(Wn[idx]);
    }
    if (idx < 3 * DF * DF){
      int k = idx >> 7, n = idx & 127; // W1: 384x128
      W1B[(((k >> 3) * 128 + n) << 3) + (k & 7)] = f2bf(W1[idx]);
    }
  }
}

// ---- CSR build ----
__global__ void k_hist(const int* dst, int* cnt){
  int e = blockIdx.x * 256 + threadIdx.x;
  if (e < NE) atomicAdd(&cnt[dst[e]], 1);
}
__global__ void k_scan1(const int* cnt, int* bsum){   // grid 196: block sums
  __shared__ int l[256];
  int t = threadIdx.x, i = blockIdx.x * 256 + t;
  l[t] = (i < NN) ? cnt[i] : 0;
  __syncthreads();
  for (int o = 128; o > 0; o >>= 1){
    if (t < o) l[t] += l[t + o];
    __syncthreads();
  }
  if (t == 0) bsum[blockIdx.x] = l[0];
}
// scan3: folds the global scan of bsum into every block; also seeds cfill
// (coarse-bucket write cursors = rp[b*256]) for the pass-A scatter.
__global__ void k_scan3(const int* cnt, const int* bsum, int* rp, int* cfill){
  __shared__ int bs[256];
  __shared__ int l[256];
  int t = threadIdx.x, i = blockIdx.x * 256 + t;
  bs[t] = (t < 196) ? bsum[t] : 0;
  int v = (i < NN) ? cnt[i] : 0;
  l[t] = v;
  __syncthreads();
  for (int o = 1; o < 256; o <<= 1){
    int xb = (t >= o) ? bs[t - o] : 0;
    int xl = (t >= o) ? l[t - o] : 0;
    __syncthreads();
    bs[t] += xb; l[t] += xl;
    __syncthreads();
  }
  int base = (blockIdx.x == 0) ? 0 : bs[blockIdx.x - 1];
  if (i < NN){
    int r = base + l[t] - v;
    rp[i] = r;
    if (t == 0) cfill[blockIdx.x] = r;   // i == blockIdx.x*256
    if (i == NN - 1) rp[NN] = base + l[t];
  }
}

// ---- scatter pass A: coarse counting sort by dst>>8 into tmp ----
// Per block: LDS hist(196) -> serial scan -> chunk reservation in cfill ->
// LDS-local sort -> contiguous run writes (~24 edges/bucket/block).
// Packed entry: src (16b) | (dst&255)<<16. Replaces the old per-edge atomic
// scatter whose 4B random writes cost 38MB of partial-line HBM writebacks.
__global__ __launch_bounds__(256) void k_scatA(
    const int* src, const int* dst, int* cfill, unsigned int* tmp){
  __shared__ unsigned int hist[196];
  __shared__ unsigned int bstart[197];
  __shared__ int gbase[196];
  __shared__ unsigned int buf[SCA_PER];
  int t = threadIdx.x;
  int e0 = blockIdx.x * SCA_PER;
  int e1 = e0 + SCA_PER; if (e1 > NE) e1 = NE;
  for (int i = t; i < 196; i += 256) hist[i] = 0;
  __syncthreads();
  for (int e = e0 + t; e < e1; e += 256) atomicAdd(&hist[dst[e] >> 8], 1u);
  __syncthreads();
  if (t == 0){
    unsigned int acc = 0;
    for (int b = 0; b < 196; ++b){ bstart[b] = acc; acc += hist[b]; }
    bstart[196] = acc;
  }
  __syncthreads();
  for (int b = t; b < 196; b += 256){
    gbase[b] = atomicAdd(&cfill[b], (int)hist[b]);
    hist[b] = bstart[b];               // reuse as placement cursor
  }
  __syncthreads();
  for (int e = e0 + t; e < e1; e += 256){
    int d = dst[e];
    unsigned int off = atomicAdd(&hist[d >> 8], 1u);
    buf[off] = (unsigned int)src[e] | ((unsigned int)(d & 255) << 16);
  }
  __syncthreads();
  int total = e1 - e0;
  for (int j = t; j < total; j += 256){
    int lo = 0, hi = 195;              // largest b with bstart[b] <= j
    while (lo < hi){ int mid = (lo + hi + 1) >> 1;
      if ((int)bstart[mid] <= j) lo = mid; else hi = mid - 1; }
    tmp[gbase[lo] + (j - (int)bstart[lo])] = buf[j];
  }
}

// ---- scatter pass B: per-bucket fine sort by dst&255 -> perm (coalesced) --
// Scan of the low-bin histogram reproduces rp[n]-rp[n0] exactly, so the
// sorted bucket writes perm[s..e) contiguously. Fallback (cap overflow,
// ~23-sigma event) uses the old global-atomic path via fill[].
__global__ __launch_bounds__(256) void k_scatB(
    const unsigned int* tmp, const int* rp, int* fill, int* perm){
  __shared__ unsigned int hist[256];
  __shared__ unsigned int ebuf[SCB_CAP];
  __shared__ unsigned int sbuf[SCB_CAP];
  int b = blockIdx.x, t = threadIdx.x;
  int n0 = b << 8;
  int n1 = n0 + 256; if (n1 > NN) n1 = NN;
  int s = rp[n0], e = rp[n1];
  int cntb = e - s;
  if (cntb <= SCB_CAP){
    for (int i = t; i < 256; i += 256) hist[i] = 0;
    __syncthreads();
    for (int i = t; i < cntb; i += 256){
      unsigned int v = tmp[s + i];
      ebuf[i] = v;
      atomicAdd(&hist[(v >> 16) & 255], 1u);
    }
    __syncthreads();
    if (t == 0){
      unsigned int acc = 0;
      for (int k = 0; k < 256; ++k){ unsigned int c = hist[k]; hist[k] = acc; acc += c; }
    }
    __syncthreads();
    for (int i = t; i < cntb; i += 256){
      unsigned int v = ebuf[i];
      unsigned int off = atomicAdd(&hist[(v >> 16) & 255], 1u);
      sbuf[off] = v;
    }
    __syncthreads();
    for (int i = t; i < cntb; i += 256) perm[s + i] = (int)(sbuf[i] & 0xFFFFu);
  } else {
    for (int i = t; i < cntb; i += 256){
      unsigned int v = tmp[s + i];
      int node = n0 + (int)((v >> 16) & 255);
      int pos = atomicAdd(&fill[node], 1);
      perm[rp[node] + pos] = (int)(v & 0xFFFFu);
    }
  }
}

// ---- mean aggregation: one wave per node, uint4 gather, 16-edge batch ----
// (r5 structure: the measured best.) 16 lanes x 16B cover one 256B row ->
// 4 edge-rows per wave-load; tail is one predicated batch. Cross-slot
// combine via shfl_xor(16,32). di computed from row pointers.
__global__ __launch_bounds__(256) void k_agg(
    const unsigned int* hb32, const int* rp, const int* perm,
    unsigned int* agg32){
  int n = blockIdx.x * 4 + (threadIdx.x >> 6);
  if (n >= NN) return;
  int l = threadIdx.x & 63;
  int rs = l >> 4, li = l & 15;        // row slot 0..3, 16B chunk 0..15
  int s = rp[n], e = rp[n + 1];
  const unsigned int* hq = hb32 + li * 4;
  float a0 = 0.f, a1 = 0.f, a2 = 0.f, a3 = 0.f;
  float a4 = 0.f, a5 = 0.f, a6 = 0.f, a7 = 0.f;
  int i = s;
  for (; i + 16 <= e; i += 16){
    int p0 = perm[i + rs];
    int p1 = perm[i + 4 + rs];
    int p2 = perm[i + 8 + rs];
    int p3 = perm[i + 12 + rs];
    uint4 x0 = *(const uint4*)(hq + (size_t)p0 * 64);
    uint4 x1 = *(const uint4*)(hq + (size_t)p1 * 64);
    uint4 x2 = *(const uint4*)(hq + (size_t)p2 * 64);
    uint4 x3 = *(const uint4*)(hq + (size_t)p3 * 64);
    a0 += __uint_as_float(x0.x << 16); a1 += __uint_as_float(x0.x & 0xffff0000u);
    a2 += __uint_as_float(x0.y << 16); a3 += __uint_as_float(x0.y & 0xffff0000u);
    a4 += __uint_as_float(x0.z << 16); a5 += __uint_as_float(x0.z & 0xffff0000u);
    a6 += __uint_as_float(x0.w << 16); a7 += __uint_as_float(x0.w & 0xffff0000u);
    a0 += __uint_as_float(x1.x << 16); a1 += __uint_as_float(x1.x & 0xffff0000u);
    a2 += __uint_as_float(x1.y << 16); a3 += __uint_as_float(x1.y & 0xffff0000u);
    a4 += __uint_as_float(x1.z << 16); a5 += __uint_as_float(x1.z & 0xffff0000u);
    a6 += __uint_as_float(x1.w << 16); a7 += __uint_as_float(x1.w & 0xffff0000u);
    a0 += __uint_as_float(x2.x << 16); a1 += __uint_as_float(x2.x & 0xffff0000u);
    a2 += __uint_as_float(x2.y << 16); a3 += __uint_as_float(x2.y & 0xffff0000u);
    a4 += __uint_as_float(x2.z << 16); a5 += __uint_as_float(x2.z & 0xffff0000u);
    a6 += __uint_as_float(x2.w << 16); a7 += __uint_as_float(x2.w & 0xffff0000u);
    a0 += __uint_as_float(x3.x << 16); a1 += __uint_as_float(x3.x & 0xffff0000u);
    a2 += __uint_as_float(x3.y << 16); a3 += __uint_as_float(x3.y & 0xffff0000u);
    a4 += __uint_as_float(x3.z << 16); a5 += __uint_as_float(x3.z & 0xffff0000u);
    a6 += __uint_as_float(x3.w << 16); a7 += __uint_as_float(x3.w & 0xffff0000u);
  }
  if (i < e){
    int i0 = i + rs, i1 = i + 4 + rs, i2 = i + 8 + rs, i3 = i + 12 + rs;
    int p0 = perm[i0 < e ? i0 : s];
    int p1 = perm[i1 < e ? i1 : s];
    int p2 = perm[i2 < e ? i2 : s];
    int p3 = perm[i3 < e ? i3 : s];
    uint4 x0 = *(const uint4*)(hq + (size_t)p0 * 64);
    uint4 x1 = *(const uint4*)(hq + (size_t)p1 * 64);
    uint4 x2 = *(const uint4*)(hq + (size_t)p2 * 64);
    uint4 x3 = *(const uint4*)(hq + (size_t)p3 * 64);
    if (i0 < e){
      a0 += __uint_as_float(x0.x << 16); a1 += __uint_as_float(x0.x & 0xffff0000u);
      a2 += __uint_as_float(x0.y << 16); a3 += __uint_as_float(x0.y & 0xffff0000u);
      a4 += __uint_as_float(x0.z << 16); a5 += __uint_as_float(x0.z & 0xffff0000u);
      a6 += __uint_as_float(x0.w << 16); a7 += __uint_as_float(x0.w & 0xffff0000u);
    }
    if (i1 < e){
      a0 += __uint_as_float(x1.x << 16); a1 += __uint_as_float(x1.x & 0xffff0000u);
      a2 += __uint_as_float(x1.y << 16); a3 += __uint_as_float(x1.y & 0xffff0000u);
      a4 += __uint_as_float(x1.z << 16); a5 += __uint_as_float(x1.z & 0xffff0000u);
      a6 += __uint_as_float(x1.w << 16); a7 += __uint_as_float(x1.w & 0xffff0000u);
    }
    if (i2 < e){
      a0 += __uint_as_float(x2.x << 16); a1 += __uint_as_float(x2.x & 0xffff0000u);
      a2 += __uint_as_float(x2.y << 16); a3 += __uint_as_float(x2.y & 0xffff0000u);
      a4 += __uint_as_float(x2.z << 16); a5 += __uint_as_float(x2.z & 0xffff0000u);
      a6 += __uint_as_float(x2.w << 16); a7 += __uint_as_float(x2.w & 0xffff0000u);
    }
    if (i3 < e){
      a0 += __uint_as_float(x3.x << 16); a1 += __uint_as_float(x3.x & 0xffff0000u);
      a2 += __uint_as_float(x3.y << 16); a3 += __uint_as_float(x3.y & 0xffff0000u);
      a4 += __uint_as_float(x3.z << 16); a5 += __uint_as_float(x3.z & 0xffff0000u);
      a6 += __uint_as_float(x3.w << 16); a7 += __uint_as_float(x3.w & 0xffff0000u);
    }
  }
  a0 += __shfl_xor(a0, 16); a1 += __shfl_xor(a1, 16);
  a2 += __shfl_xor(a2, 16); a3 += __shfl_xor(a3, 16);
  a4 += __shfl_xor(a4, 16); a5 += __shfl_xor(a5, 16);
  a6 += __shfl_xor(a6, 16); a7 += __shfl_xor(a7, 16);
  a0 += __shfl_xor(a0, 32); a1 += __shfl_xor(a1, 32);
  a2 += __shfl_xor(a2, 32); a3 += __shfl_xor(a3, 32);
  a4 += __shfl_xor(a4, 32); a5 += __shfl_xor(a5, 32);
  a6 += __shfl_xor(a6, 32); a7 += __shfl_xor(a7, 32);
  if (rs == 0){
    float di = 1.0f / fmaxf((float)(e - s), 1.0f);
    uint4 r;
    r.x = (unsigned int)f2bf(a0 * di) | ((unsigned int)f2bf(a1 * di) << 16);
    r.y = (unsigned int)f2bf(a2 * di) | ((unsigned int)f2bf(a3 * di) << 16);
    r.z = (unsigned int)f2bf(a4 * di) | ((unsigned int)f2bf(a5 * di) << 16);
    r.w = (unsigned int)f2bf(a6 * di) | ((unsigned int)f2bf(a7 * di) << 16);
    *(uint4*)(agg32 + (size_t)n * 64 + li * 4) = r;
  }
}

// ---- layer GEMM via MFMA, 2 row-tiles per wave (r8 winner) ----
__global__ __launch_bounds__(256) void k_layer_mfma(
    const unsigned short* hb, const unsigned short* aggb,
    const unsigned short* WsB, const unsigned short* WnB,
    const float* bias, unsigned short* hout){
  int t = threadIdx.x;
  int w = t >> 6, l = t & 63;
  int m = l & 15, q = l >> 4;
  int r0 = blockIdx.x * 128 + w * 16;          // tile0 base; tile1 = +64
  int arow0 = r0 + m;       if (arow0 > NN - 1) arow0 = NN - 1;
  int arow1 = r0 + 64 + m;  if (arow1 > NN - 1) arow1 = NN - 1;
  const unsigned short* hp0 = hb   + (size_t)arow0 * DF + q * 8;
  const unsigned short* ap0 = aggb + (size_t)arow0 * DF + q * 8;
  const unsigned short* hp1 = hb   + (size_t)arow1 * DF + q * 8;
  const unsigned short* ap1 = aggb + (size_t)arow1 * DF + q * 8;
  f32x4 acc0[8], acc1[8];
  for (int ct = 0; ct < 8; ++ct){
    float bbc = bias[ct * 16 + m];
    acc0[ct] = (f32x4){bbc, bbc, bbc, bbc};
    acc1[ct] = (f32x4){bbc, bbc, bbc, bbc};
  }
  for (int kt = 0; kt < 4; ++kt){
    bf16x8 a_h0 = *(const bf16x8*)(hp0 + kt * 32);
    bf16x8 a_g0 = *(const bf16x8*)(ap0 + kt * 32);
    bf16x8 a_h1 = *(const bf16x8*)(hp1 + kt * 32);
    bf16x8 a_g1 = *(const bf16x8*)(ap1 + kt * 32);
    int kg = kt * 4 + q;
    for (int ct = 0; ct < 8; ++ct){
      bf16x8 b_s = *(const bf16x8*)(WsB + (((kg << 7) + ct * 16 + m) << 3));
      bf16x8 b_n = *(const bf16x8*)(WnB + (((kg << 7) + ct * 16 + m) << 3));
      acc0[ct] = __builtin_amdgcn_mfma_f32_16x16x32_bf16(a_h0, b_s, acc0[ct], 0, 0, 0);
      acc0[ct] = __builtin_amdgcn_mfma_f32_16x16x32_bf16(a_g0, b_n, acc0[ct], 0, 0, 0);
      acc1[ct] = __builtin_amdgcn_mfma_f32_16x16x32_bf16(a_h1, b_s, acc1[ct], 0, 0, 0);
      acc1[ct] = __builtin_amdgcn_mfma_f32_16x16x32_bf16(a_g1, b_n, acc1[ct], 0, 0, 0);
    }
  }
  for (int ct = 0; ct < 8; ++ct){
    int col = ct * 16 + m;
    for (int reg = 0; reg < 4; ++reg){
      int row0 = r0 + q * 4 + reg;
      int row1 = row0 + 64;
      if (row0 < NN) hout[(size_t)row0 * DF + col] = f2bf(fmaxf(acc0[ct][reg], 0.f));
      if (row1 < NN) hout[(size_t)row1 * DF + col] = f2bf(fmaxf(acc1[ct][reg], 0.f));
    }
  }
}

// ---- pair GEMM via MFMA + fused BN column stats; src/tar via blockIdx.y ----
__global__ __launch_bounds__(256) void k_pair_mfma(
    const unsigned short* h2,
    const int* x1, const int* x2, const int* x1t, const int* x2t,
    const unsigned short* W1B, const float* b1, float* zbase, float* stats){
  __shared__ __align__(16) unsigned short F[64 * 392];
  __shared__ float csum[128], csq[128];
  int g = blockIdx.y;
  const int* ia = g ? x1t : x1;
  const int* ib = g ? x2t : x2;
  float* z = zbase + (size_t)g * NB * DF;
  int t = threadIdx.x;
  if (t < 128){ csum[t] = 0.f; csq[t] = 0.f; }
  int r0 = blockIdx.x * 64;
  int i = t >> 2, qq = t & 3;
  int r = r0 + i;
  int a = ia[r], b = ib[r];
  const unsigned short* pa = h2 + (size_t)a * DF + qq * 32;
  const unsigned short* pb = h2 + (size_t)b * DF + qq * 32;
  unsigned short* fr = F + i * 392;
  for (int jj = 0; jj < 4; ++jj){
    bf16x8 va = *(const bf16x8*)(pa + jj * 8);
    bf16x8 vb = *(const bf16x8*)(pb + jj * 8);
    *(bf16x8*)(fr + qq * 32 + jj * 8) = va;
    *(bf16x8*)(fr + 128 + qq * 32 + jj * 8) = vb;
    unsigned short d[8];
    for (int e = 0; e < 8; ++e){
      float fa = bf2f((unsigned short)va[e]);
      float fb = bf2f((unsigned short)vb[e]);
      d[e] = f2bf(fabsf(fa - fb));
    }
    *(bf16x8*)(fr + 256 + qq * 32 + jj * 8) = *(bf16x8*)d;
  }
  __syncthreads();
  int w = t >> 6, l = t & 63;
  int m = l & 15, q = l >> 4;
  int rl = w * 16 + m;
  f32x4 acc[8];
  for (int ct = 0; ct < 8; ++ct){
    float bbc = b1[ct * 16 + m];
    acc[ct] = (f32x4){bbc, bbc, bbc, bbc};
  }
  for (int kt = 0; kt < 12; ++kt){
    bf16x8 af = *(const bf16x8*)(F + rl * 392 + kt * 32 + q * 8);
    int kg = kt * 4 + q;
    for (int ct = 0; ct < 8; ++ct){
      bf16x8 bfr = *(const bf16x8*)(W1B + (((kg << 7) + ct * 16 + m) << 3));
      acc[ct] = __builtin_amdgcn_mfma_f32_16x16x32_bf16(af, bfr, acc[ct], 0, 0, 0);
    }
  }
  for (int ct = 0; ct < 8; ++ct){
    int col = ct * 16 + m;
    int row = r0 + w * 16 + q * 4;
    float s = 0.f, s2 = 0.f;
    for (int reg = 0; reg < 4; ++reg){
      float v = acc[ct][reg];
      z[(size_t)(row + reg) * DF + col] = v;
      s += v; s2 += v * v;
    }
    atomicAdd(&csum[col], s);
    atomicAdd(&csq[col], s2);
  }
  __syncthreads();
  if (t < 128){
    atomicAdd(&stats[g * 256 + t], csum[t]);
    atomicAdd(&stats[g * 256 + 128 + t], csq[t]);
  }
}

// ---- fused BN-normalize + relu + (src only) h_p GEMM, barrier-free ----
__global__ __launch_bounds__(256) void k_norm_hp(
    const float* zbase, const float* stats,
    const float* gamma, const float* beta,
    const float* W2, const float* b2, float* mmd_base, float* hp){
  int g = blockIdx.y;
  int t = threadIdx.x;
  int w = t >> 6, l = t & 63;
  int c0 = l * 2, c1 = c0 + 1;
  float m0 = stats[g * 256 + c0] * (1.0f / NB);
  float m1 = stats[g * 256 + c1] * (1.0f / NB);
  float v0 = stats[g * 256 + 128 + c0] * (1.0f / NB) - m0 * m0;
  float v1 = stats[g * 256 + 128 + c1] * (1.0f / NB) - m1 * m1;
  float is0 = 1.0f / sqrtf(v0 + 1e-5f);
  float is1 = 1.0f / sqrtf(v1 + 1e-5f);
  float ga0 = gamma[c0], ga1 = gamma[c1];
  float be0 = beta[c0], be1 = beta[c1];
  float w200 = W2[c0 * 2], w201 = W2[c0 * 2 + 1];
  float w210 = W2[c1 * 2], w211 = W2[c1 * 2 + 1];
  const float* z = zbase + (size_t)g * NB * DF;
  float* mmd = mmd_base + (size_t)g * NB * DF;
  int rbase = blockIdx.x * 16 + w * 4;
  for (int rr = 0; rr < 4; ++rr){
    int row = rbase + rr;
    float2 zv = *(const float2*)(z + (size_t)row * DF + c0);
    float y0 = fmaxf((zv.x - m0) * is0 * ga0 + be0, 0.f);
    float y1 = fmaxf((zv.y - m1) * is1 * ga1 + be1, 0.f);
    float2 yv; yv.x = y0; yv.y = y1;
    *(float2*)(mmd + (size_t)row * DF + c0) = yv;
    if (g == 0){
      float s0 = y0 * w200 + y1 * w210;
      float s1 = y0 * w201 + y1 * w211;
      for (int o = 32; o > 0; o >>= 1){
        s0 += __shfl_xor(s0, o);
        s1 += __shfl_xor(s1, o);
      }
      if (l == 0){
        hp[row * 2]     = s0 + b2[0];
        hp[row * 2 + 1] = s1 + b2[1];
      }
    }
  }
}

extern "C" __attribute__((used, visibility("default")))
void kernel_launch(void* const* d_in, const int* in_sizes, int n_in,
                   void* d_out, int out_size, void* d_ws, size_t ws_size,
                   hipStream_t stream){
  const float* h_in  = (const float*)d_in[0];
  const int* esrc = (const int*)d_in[1];
  const int* edst = (const int*)d_in[2];
  const int* x1   = (const int*)d_in[3];
  const int* x2   = (const int*)d_in[4];
  const int* x1t  = (const int*)d_in[5];
  const int* x2t  = (const int*)d_in[6];
  const float* Wself = (const float*)d_in[7];
  const float* Wneigh= (const float*)d_in[8];
  const float* bconv = (const float*)d_in[9];
  const float* W1    = (const float*)d_in[10];
  const float* b1    = (const float*)d_in[11];
  const float* gamma = (const float*)d_in[12];
  const float* beta  = (const float*)d_in[13];
  const float* W2    = (const float*)d_in[14];
  const float* b2    = (const float*)d_in[15];
  float* out = (float*)d_out;                   // fp32 outputs
  float* hp_out   = out;                        // [NB,2]
  float* mmd_base = out + 2 * NB;               // [2][NB,DF] contiguous

  // ---- workspace layout (~48.3 MB) ----
  float* zreg  = (float*)d_ws;                       // 2*NB*DF f32 (src|tar)
  unsigned short* aggb = (unsigned short*)zreg;      // alias (dead before z)
  float* stats = zreg + (size_t)2 * NB * DF;         // 512
  float* mstd  = stats + 512;                        // 512 (layout pad)
  float* dinv  = mstd + 512;                         // 50,048 (unused slot)
  int* cnt  = (int*)(dinv + 50048);                  // 50,000
  int* fill = cnt + NN;                              // 50,000
  int* rp   = fill + NN;                             // 50,016
  int* perm = rp + 50016;                            // 600,000
  int* bsum = perm + 600000;                         // 256
  int* cfill = bsum + 256;                           // 256 (196 used)
  unsigned short* h_c = (unsigned short*)(cfill + 256);   // NN*DF u16
  unsigned short* h1b = h_c + (size_t)NN * DF;            // NN*DF u16
  unsigned short* h2b = h_c;                 // alias: h_c dead after layer 0
  unsigned short* WsB = h1b + (size_t)NN * DF;  // 2*DF*DF u16 (both layers)
  unsigned short* WnB = WsB + 2 * DF * DF;      // 2*DF*DF u16
  unsigned short* W1B = WnB + 2 * DF * DF;      // 3*DF*DF u16
  unsigned int* tmp = (unsigned int*)(W1B + 3 * DF * DF); // NE u32 (pass A)
  (void)dinv;

  // fused prelude: h cast + zeroing + weight swizzle
  k_prelude<<<3710, 256, 0, stream>>>(h_in, h_c, Wself, Wneigh, W1,
                                      WsB, WnB, W1B, cnt, stats);

  // CSR build: hist -> scan -> two-pass counting-sort scatter
  k_hist<<<(NE + 255) / 256, 256, 0, stream>>>(edst, cnt);
  k_scan1<<<196, 256, 0, stream>>>(cnt, bsum);
  k_scan3<<<196, 256, 0, stream>>>(cnt, bsum, rp, cfill);
  k_scatA<<<SCA_B, 256, 0, stream>>>(esrc, edst, cfill, tmp);
  k_scatB<<<196, 256, 0, stream>>>(tmp, rp, fill, perm);

  // SAGE layer 0: h_c -> h1b
  k_agg<<<(NN + 3) / 4, 256, 0, stream>>>((const unsigned int*)h_c, rp, perm,
                                          (unsigned int*)aggb);
  k_layer_mfma<<<(NN + 127) / 128, 256, 0, stream>>>(h_c, aggb, WsB, WnB,
                                                     bconv, h1b);
  // SAGE layer 1: h1b -> h2b
  k_agg<<<(NN + 3) / 4, 256, 0, stream>>>((const unsigned int*)h1b, rp, perm,
                                          (unsigned int*)aggb);
  k_layer_mfma<<<(NN + 127) / 128, 256, 0, stream>>>(h1b, aggb, WsB + DF * DF,
                                                     WnB + DF * DF, bconv + DF,
                                                     h2b);

  // head: pair GEMM (+ fused col-stats), then normalize (+ fused h_p)
  k_pair_mfma<<<dim3(NB / 64, 2), 256, 0, stream>>>(h2b, x1, x2, x1t, x2t,
                                                    W1B, b1, zreg, stats);
  k_norm_hp<<<dim3(NB / 16, 2), 256, 0, stream>>>(zreg, stats, gamma, beta,
                                                  W2, b2, mmd_base, hp_out);
}

// Round 11
// 269.838 us; speedup vs baseline: 1.0593x; 1.0593x over previous
//
#include <hip/hip_runtime.h>

#define NN 50000   // nodes
#define NE 600000  // edges
#define DF 128     // features
#define NB 16384   // pair batch
#define SCA_B 256                 // pass-A blocks (1 per CU)
#define SCA_PER ((NE + SCA_B - 1) / SCA_B)   // 2344 edges/block
#define SCB_CAP 4352              // pass-B LDS edge capacity (23 sigma)

typedef short bf16x8 __attribute__((ext_vector_type(8)));
typedef float f32x4 __attribute__((ext_vector_type(4)));

__device__ __forceinline__ float bf2f(unsigned short u){
  return __uint_as_float(((unsigned int)u) << 16);
}
__device__ __forceinline__ unsigned short f2bf(float x){
  unsigned int b = __float_as_uint(x);
  return (unsigned short)((b + 0x7FFFu + ((b >> 16) & 1u)) >> 16);
}

// Original template symbol (defined, never launched).
__global__ void GraphSAGE_8504035246140_kernel(){ }

// ---- fused prelude: h cast | zero cnt/fill | zero stats | weight swizzle ----
__global__ __launch_bounds__(256) void k_prelude(
    const float* h_in, unsigned short* h_c,
    const float* Ws, const float* Wn, const float* W1,
    unsigned short* WsB, unsigned short* WnB, unsigned short* W1B,
    int* cnt, float* stats){
  int b = blockIdx.x, t = threadIdx.x;
  if (b < 3125){                       // 3125*256 == NN*DF/8 exactly
    int i = b * 256 + t;
    const float4* s = (const float4*)h_in;
    float4 v0 = s[i * 2], v1 = s[i * 2 + 1];
    unsigned short d[8] = {f2bf(v0.x), f2bf(v0.y), f2bf(v0.z), f2bf(v0.w),
                           f2bf(v1.x), f2bf(v1.y), f2bf(v1.z), f2bf(v1.w)};
    *(bf16x8*)(h_c + i * 8) = *(bf16x8*)d;
  } else if (b < 3516){
    int i = (b - 3125) * 256 + t;
    if (i < 2 * NN) cnt[i] = 0;        // cnt + fill (adjacent)
  } else if (b < 3518){
    int i = (b - 3516) * 256 + t;
    if (i < 512) stats[i] = 0.f;
  } else {
    int idx = (b - 3518) * 256 + t;    // 192 blocks -> 49152 threads
    if (idx < 2 * DF * DF){
      int layer = idx >> 14;
      int e = idx & (DF * DF - 1);
      int k = e >> 7, n = e & 127;
      int dst = layer * DF * DF + (((k >> 3) * 128 + n) << 3) + (k & 7);
      WsB[dst] = f2bf(Ws[idx]);
      WnB[dst] = f2bf(Wn[idx]);
    }
    if (idx < 3 * DF * DF){
      int k = idx >> 7, n = idx & 127; // W1: 384x128
      W1B[(((k >> 3) * 128 + n) << 3) + (k & 7)] = f2bf(W1[idx]);
    }
  }
}

// ---- CSR build ----
__global__ void k_hist(const int* dst, int* cnt){
  int e = blockIdx.x * 256 + threadIdx.x;
  if (e < NE) atomicAdd(&cnt[dst[e]], 1);
}
__global__ void k_scan1(const int* cnt, int* bsum){   // grid 196: block sums
  __shared__ int l[256];
  int t = threadIdx.x, i = blockIdx.x * 256 + t;
  l[t] = (i < NN) ? cnt[i] : 0;
  __syncthreads();
  for (int o = 128; o > 0; o >>= 1){
    if (t < o) l[t] += l[t + o];
    __syncthreads();
  }
  if (t == 0) bsum[blockIdx.x] = l[0];
}
// scan3: folds the global scan of bsum into every block; also seeds cfill
// (coarse-bucket write cursors = rp[b*256]) for the pass-A scatter.
__global__ void k_scan3(const int* cnt, const int* bsum, int* rp, int* cfill){
  __shared__ int bs[256];
  __shared__ int l[256];
  int t = threadIdx.x, i = blockIdx.x * 256 + t;
  bs[t] = (t < 196) ? bsum[t] : 0;
  int v = (i < NN) ? cnt[i] : 0;
  l[t] = v;
  __syncthreads();
  for (int o = 1; o < 256; o <<= 1){
    int xb = (t >= o) ? bs[t - o] : 0;
    int xl = (t >= o) ? l[t - o] : 0;
    __syncthreads();
    bs[t] += xb; l[t] += xl;
    __syncthreads();
  }
  int base = (blockIdx.x == 0) ? 0 : bs[blockIdx.x - 1];
  if (i < NN){
    int r = base + l[t] - v;
    rp[i] = r;
    if (t == 0) cfill[blockIdx.x] = r;   // i == blockIdx.x*256
    if (i == NN - 1) rp[NN] = base + l[t];
  }
}

// ---- scatter pass A v2: coarse bucket (dst>>8) chunk write, no local sort --
// Per block: LDS hist(196) -> parallel chunk reservation in cfill -> direct
// placement tmp[cursor[b]++] = src|(dst&255)<<16. Chunks ~12 entries span
// 1-2 lines -> ~2x write amp (5MB vs the old scatter's 38MB partial-line
// writebacks). No buf / binary search / serial scan (r9's serialization).
__global__ __launch_bounds__(256) void k_scatA(
    const int* src, const int* dst, int* cfill, unsigned int* tmp){
  __shared__ unsigned int hist[196];
  __shared__ unsigned int cursor[196];
  int t = threadIdx.x;
  int e0 = blockIdx.x * SCA_PER;
  int e1 = e0 + SCA_PER; if (e1 > NE) e1 = NE;
  if (t < 196) hist[t] = 0;
  __syncthreads();
  for (int e = e0 + t; e < e1; e += 256) atomicAdd(&hist[dst[e] >> 8], 1u);
  __syncthreads();
  if (t < 196) cursor[t] = (unsigned int)atomicAdd(&cfill[t], (int)hist[t]);
  __syncthreads();
  for (int e = e0 + t; e < e1; e += 256){
    int d = dst[e];
    unsigned int off = atomicAdd(&cursor[d >> 8], 1u);
    tmp[off] = (unsigned int)src[e] | ((unsigned int)(d & 255) << 16);
  }
}

// ---- scatter pass B v2: per-bucket fine sort by dst&255 -> perm ----------
// Parallel Hillis-Steele scan over the 256 bins (was serial t==0 in r9).
// Scan of the low-bin histogram reproduces rp[n]-rp[n0] exactly, so the
// sorted bucket writes perm[s..e) contiguously. Fallback (cap overflow,
// ~23-sigma event) uses the old global-atomic path via fill[].
__global__ __launch_bounds__(256) void k_scatB(
    const unsigned int* tmp, const int* rp, int* fill, int* perm){
  __shared__ unsigned int hist[256];
  __shared__ unsigned int sc[256];
  __shared__ unsigned int ebuf[SCB_CAP];
  __shared__ unsigned int sbuf[SCB_CAP];
  int b = blockIdx.x, t = threadIdx.x;
  int n0 = b << 8;
  int n1 = n0 + 256; if (n1 > NN) n1 = NN;
  int s = rp[n0], e = rp[n1];
  int cntb = e - s;
  if (cntb <= SCB_CAP){
    hist[t] = 0;
    __syncthreads();
    for (int i = t; i < cntb; i += 256){
      unsigned int v = tmp[s + i];
      ebuf[i] = v;
      atomicAdd(&hist[(v >> 16) & 255], 1u);
    }
    __syncthreads();
    unsigned int cntk = hist[t];
    sc[t] = cntk;
    __syncthreads();
    for (int o = 1; o < 256; o <<= 1){
      unsigned int x = (t >= o) ? sc[t - o] : 0;
      __syncthreads();
      sc[t] += x;
      __syncthreads();
    }
    hist[t] = sc[t] - cntk;              // exclusive bin start
    __syncthreads();
    for (int i = t; i < cntb; i += 256){
      unsigned int v = ebuf[i];
      unsigned int off = atomicAdd(&hist[(v >> 16) & 255], 1u);
      sbuf[off] = v;
    }
    __syncthreads();
    for (int i = t; i < cntb; i += 256) perm[s + i] = (int)(sbuf[i] & 0xFFFFu);
  } else {
    for (int i = t; i < cntb; i += 256){
      unsigned int v = tmp[s + i];
      int node = n0 + (int)((v >> 16) & 255);
      int pos = atomicAdd(&fill[node], 1);
      perm[rp[node] + pos] = (int)(v & 0xFFFFu);
    }
  }
}

// ---- mean aggregation: one wave per node, uint4 gather, 16-edge batch ----
// (r5 structure: the measured best.) 16 lanes x 16B cover one 256B row ->
// 4 edge-rows per wave-load; tail is one predicated batch. Cross-slot
// combine via shfl_xor(16,32). di computed from row pointers.
__global__ __launch_bounds__(256) void k_agg(
    const unsigned int* hb32, const int* rp, const int* perm,
    unsigned int* agg32){
  int n = blockIdx.x * 4 + (threadIdx.x >> 6);
  if (n >= NN) return;
  int l = threadIdx.x & 63;
  int rs = l >> 4, li = l & 15;        // row slot 0..3, 16B chunk 0..15
  int s = rp[n], e = rp[n + 1];
  const unsigned int* hq = hb32 + li * 4;
  float a0 = 0.f, a1 = 0.f, a2 = 0.f, a3 = 0.f;
  float a4 = 0.f, a5 = 0.f, a6 = 0.f, a7 = 0.f;
  int i = s;
  for (; i + 16 <= e; i += 16){
    int p0 = perm[i + rs];
    int p1 = perm[i + 4 + rs];
    int p2 = perm[i + 8 + rs];
    int p3 = perm[i + 12 + rs];
    uint4 x0 = *(const uint4*)(hq + (size_t)p0 * 64);
    uint4 x1 = *(const uint4*)(hq + (size_t)p1 * 64);
    uint4 x2 = *(const uint4*)(hq + (size_t)p2 * 64);
    uint4 x3 = *(const uint4*)(hq + (size_t)p3 * 64);
    a0 += __uint_as_float(x0.x << 16); a1 += __uint_as_float(x0.x & 0xffff0000u);
    a2 += __uint_as_float(x0.y << 16); a3 += __uint_as_float(x0.y & 0xffff0000u);
    a4 += __uint_as_float(x0.z << 16); a5 += __uint_as_float(x0.z & 0xffff0000u);
    a6 += __uint_as_float(x0.w << 16); a7 += __uint_as_float(x0.w & 0xffff0000u);
    a0 += __uint_as_float(x1.x << 16); a1 += __uint_as_float(x1.x & 0xffff0000u);
    a2 += __uint_as_float(x1.y << 16); a3 += __uint_as_float(x1.y & 0xffff0000u);
    a4 += __uint_as_float(x1.z << 16); a5 += __uint_as_float(x1.z & 0xffff0000u);
    a6 += __uint_as_float(x1.w << 16); a7 += __uint_as_float(x1.w & 0xffff0000u);
    a0 += __uint_as_float(x2.x << 16); a1 += __uint_as_float(x2.x & 0xffff0000u);
    a2 += __uint_as_float(x2.y << 16); a3 += __uint_as_float(x2.y & 0xffff0000u);
    a4 += __uint_as_float(x2.z << 16); a5 += __uint_as_float(x2.z & 0xffff0000u);
    a6 += __uint_as_float(x2.w << 16); a7 += __uint_as_float(x2.w & 0xffff0000u);
    a0 += __uint_as_float(x3.x << 16); a1 += __uint_as_float(x3.x & 0xffff0000u);
    a2 += __uint_as_float(x3.y << 16); a3 += __uint_as_float(x3.y & 0xffff0000u);
    a4 += __uint_as_float(x3.z << 16); a5 += __uint_as_float(x3.z & 0xffff0000u);
    a6 += __uint_as_float(x3.w << 16); a7 += __uint_as_float(x3.w & 0xffff0000u);
  }
  if (i < e){
    int i0 = i + rs, i1 = i + 4 + rs, i2 = i + 8 + rs, i3 = i + 12 + rs;
    int p0 = perm[i0 < e ? i0 : s];
    int p1 = perm[i1 < e ? i1 : s];
    int p2 = perm[i2 < e ? i2 : s];
    int p3 = perm[i3 < e ? i3 : s];
    uint4 x0 = *(const uint4*)(hq + (size_t)p0 * 64);
    uint4 x1 = *(const uint4*)(hq + (size_t)p1 * 64);
    uint4 x2 = *(const uint4*)(hq + (size_t)p2 * 64);
    uint4 x3 = *(const uint4*)(hq + (size_t)p3 * 64);
    if (i0 < e){
      a0 += __uint_as_float(x0.x << 16); a1 += __uint_as_float(x0.x & 0xffff0000u);
      a2 += __uint_as_float(x0.y << 16); a3 += __uint_as_float(x0.y & 0xffff0000u);
      a4 += __uint_as_float(x0.z << 16); a5 += __uint_as_float(x0.z & 0xffff0000u);
      a6 += __uint_as_float(x0.w << 16); a7 += __uint_as_float(x0.w & 0xffff0000u);
    }
    if (i1 < e){
      a0 += __uint_as_float(x1.x << 16); a1 += __uint_as_float(x1.x & 0xffff0000u);
      a2 += __uint_as_float(x1.y << 16); a3 += __uint_as_float(x1.y & 0xffff0000u);
      a4 += __uint_as_float(x1.z << 16); a5 += __uint_as_float(x1.z & 0xffff0000u);
      a6 += __uint_as_float(x1.w << 16); a7 += __uint_as_float(x1.w & 0xffff0000u);
    }
    if (i2 < e){
      a0 += __uint_as_float(x2.x << 16); a1 += __uint_as_float(x2.x & 0xffff0000u);
      a2 += __uint_as_float(x2.y << 16); a3 += __uint_as_float(x2.y & 0xffff0000u);
      a4 += __uint_as_float(x2.z << 16); a5 += __uint_as_float(x2.z & 0xffff0000u);
      a6 += __uint_as_float(x2.w << 16); a7 += __uint_as_float(x2.w & 0xffff0000u);
    }
    if (i3 < e){
      a0 += __uint_as_float(x3.x << 16); a1 += __uint_as_float(x3.x & 0xffff0000u);
      a2 += __uint_as_float(x3.y << 16); a3 += __uint_as_float(x3.y & 0xffff0000u);
      a4 += __uint_as_float(x3.z << 16); a5 += __uint_as_float(x3.z & 0xffff0000u);
      a6 += __uint_as_float(x3.w << 16); a7 += __uint_as_float(x3.w & 0xffff0000u);
    }
  }
  a0 += __shfl_xor(a0, 16); a1 += __shfl_xor(a1, 16);
  a2 += __shfl_xor(a2, 16); a3 += __shfl_xor(a3, 16);
  a4 += __shfl_xor(a4, 16); a5 += __shfl_xor(a5, 16);
  a6 += __shfl_xor(a6, 16); a7 += __shfl_xor(a7, 16);
  a0 += __shfl_xor(a0, 32); a1 += __shfl_xor(a1, 32);
  a2 += __shfl_xor(a2, 32); a3 += __shfl_xor(a3, 32);
  a4 += __shfl_xor(a4, 32); a5 += __shfl_xor(a5, 32);
  a6 += __shfl_xor(a6, 32); a7 += __shfl_xor(a7, 32);
  if (rs == 0){
    float di = 1.0f / fmaxf((float)(e - s), 1.0f);
    uint4 r;
    r.x = (unsigned int)f2bf(a0 * di) | ((unsigned int)f2bf(a1 * di) << 16);
    r.y = (unsigned int)f2bf(a2 * di) | ((unsigned int)f2bf(a3 * di) << 16);
    r.z = (unsigned int)f2bf(a4 * di) | ((unsigned int)f2bf(a5 * di) << 16);
    r.w = (unsigned int)f2bf(a6 * di) | ((unsigned int)f2bf(a7 * di) << 16);
    *(uint4*)(agg32 + (size_t)n * 64 + li * 4) = r;
  }
}

// ---- layer GEMM via MFMA, 2 row-tiles per wave (r8 winner) ----
__global__ __launch_bounds__(256) void k_layer_mfma(
    const unsigned short* hb, const unsigned short* aggb,
    const unsigned short* WsB, const unsigned short* WnB,
    const float* bias, unsigned short* hout){
  int t = threadIdx.x;
  int w = t >> 6, l = t & 63;
  int m = l & 15, q = l >> 4;
  int r0 = blockIdx.x * 128 + w * 16;          // tile0 base; tile1 = +64
  int arow0 = r0 + m;       if (arow0 > NN - 1) arow0 = NN - 1;
  int arow1 = r0 + 64 + m;  if (arow1 > NN - 1) arow1 = NN - 1;
  const unsigned short* hp0 = hb   + (size_t)arow0 * DF + q * 8;
  const unsigned short* ap0 = aggb + (size_t)arow0 * DF + q * 8;
  const unsigned short* hp1 = hb   + (size_t)arow1 * DF + q * 8;
  const unsigned short* ap1 = aggb + (size_t)arow1 * DF + q * 8;
  f32x4 acc0[8], acc1[8];
  for (int ct = 0; ct < 8; ++ct){
    float bbc = bias[ct * 16 + m];
    acc0[ct] = (f32x4){bbc, bbc, bbc, bbc};
    acc1[ct] = (f32x4){bbc, bbc, bbc, bbc};
  }
  for (int kt = 0; kt < 4; ++kt){
    bf16x8 a_h0 = *(const bf16x8*)(hp0 + kt * 32);
    bf16x8 a_g0 = *(const bf16x8*)(ap0 + kt * 32);
    bf16x8 a_h1 = *(const bf16x8*)(hp1 + kt * 32);
    bf16x8 a_g1 = *(const bf16x8*)(ap1 + kt * 32);
    int kg = kt * 4 + q;
    for (int ct = 0; ct < 8; ++ct){
      bf16x8 b_s = *(const bf16x8*)(WsB + (((kg << 7) + ct * 16 + m) << 3));
      bf16x8 b_n = *(const bf16x8*)(WnB + (((kg << 7) + ct * 16 + m) << 3));
      acc0[ct] = __builtin_amdgcn_mfma_f32_16x16x32_bf16(a_h0, b_s, acc0[ct], 0, 0, 0);
      acc0[ct] = __builtin_amdgcn_mfma_f32_16x16x32_bf16(a_g0, b_n, acc0[ct], 0, 0, 0);
      acc1[ct] = __builtin_amdgcn_mfma_f32_16x16x32_bf16(a_h1, b_s, acc1[ct], 0, 0, 0);
      acc1[ct] = __builtin_amdgcn_mfma_f32_16x16x32_bf16(a_g1, b_n, acc1[ct], 0, 0, 0);
    }
  }
  for (int ct = 0; ct < 8; ++ct){
    int col = ct * 16 + m;
    for (int reg = 0; reg < 4; ++reg){
      int row0 = r0 + q * 4 + reg;
      int row1 = row0 + 64;
      if (row0 < NN) hout[(size_t)row0 * DF + col] = f2bf(fmaxf(acc0[ct][reg], 0.f));
      if (row1 < NN) hout[(size_t)row1 * DF + col] = f2bf(fmaxf(acc1[ct][reg], 0.f));
    }
  }
}

// ---- pair GEMM via MFMA + fused BN column stats; src/tar via blockIdx.y ----
__global__ __launch_bounds__(256) void k_pair_mfma(
    const unsigned short* h2,
    const int* x1, const int* x2, const int* x1t, const int* x2t,
    const unsigned short* W1B, const float* b1, float* zbase, float* stats){
  __shared__ __align__(16) unsigned short F[64 * 392];
  __shared__ float csum[128], csq[128];
  int g = blockIdx.y;
  const int* ia = g ? x1t : x1;
  const int* ib = g ? x2t : x2;
  float* z = zbase + (size_t)g * NB * DF;
  int t = threadIdx.x;
  if (t < 128){ csum[t] = 0.f; csq[t] = 0.f; }
  int r0 = blockIdx.x * 64;
  int i = t >> 2, qq = t & 3;
  int r = r0 + i;
  int a = ia[r], b = ib[r];
  const unsigned short* pa = h2 + (size_t)a * DF + qq * 32;
  const unsigned short* pb = h2 + (size_t)b * DF + qq * 32;
  unsigned short* fr = F + i * 392;
  for (int jj = 0; jj < 4; ++jj){
    bf16x8 va = *(const bf16x8*)(pa + jj * 8);
    bf16x8 vb = *(const bf16x8*)(pb + jj * 8);
    *(bf16x8*)(fr + qq * 32 + jj * 8) = va;
    *(bf16x8*)(fr + 128 + qq * 32 + jj * 8) = vb;
    unsigned short d[8];
    for (int e = 0; e < 8; ++e){
      float fa = bf2f((unsigned short)va[e]);
      float fb = bf2f((unsigned short)vb[e]);
      d[e] = f2bf(fabsf(fa - fb));
    }
    *(bf16x8*)(fr + 256 + qq * 32 + jj * 8) = *(bf16x8*)d;
  }
  __syncthreads();
  int w = t >> 6, l = t & 63;
  int m = l & 15, q = l >> 4;
  int rl = w * 16 + m;
  f32x4 acc[8];
  for (int ct = 0; ct < 8; ++ct){
    float bbc = b1[ct * 16 + m];
    acc[ct] = (f32x4){bbc, bbc, bbc, bbc};
  }
  for (int kt = 0; kt < 12; ++kt){
    bf16x8 af = *(const bf16x8*)(F + rl * 392 + kt * 32 + q * 8);
    int kg = kt * 4 + q;
    for (int ct = 0; ct < 8; ++ct){
      bf16x8 bfr = *(const bf16x8*)(W1B + (((kg << 7) + ct * 16 + m) << 3));
      acc[ct] = __builtin_amdgcn_mfma_f32_16x16x32_bf16(af, bfr, acc[ct], 0, 0, 0);
    }
  }
  for (int ct = 0; ct < 8; ++ct){
    int col = ct * 16 + m;
    int row = r0 + w * 16 + q * 4;
    float s = 0.f, s2 = 0.f;
    for (int reg = 0; reg < 4; ++reg){
      float v = acc[ct][reg];
      z[(size_t)(row + reg) * DF + col] = v;
      s += v; s2 += v * v;
    }
    atomicAdd(&csum[col], s);
    atomicAdd(&csq[col], s2);
  }
  __syncthreads();
  if (t < 128){
    atomicAdd(&stats[g * 256 + t], csum[t]);
    atomicAdd(&stats[g * 256 + 128 + t], csq[t]);
  }
}

// ---- fused BN-normalize + relu + (src only) h_p GEMM, barrier-free ----
__global__ __launch_bounds__(256) void k_norm_hp(
    const float* zbase, const float* stats,
    const float* gamma, const float* beta,
    const float* W2, const float* b2, float* mmd_base, float* hp){
  int g = blockIdx.y;
  int t = threadIdx.x;
  int w = t >> 6, l = t & 63;
  int c0 = l * 2, c1 = c0 + 1;
  float m0 = stats[g * 256 + c0] * (1.0f / NB);
  float m1 = stats[g * 256 + c1] * (1.0f / NB);
  float v0 = stats[g * 256 + 128 + c0] * (1.0f / NB) - m0 * m0;
  float v1 = stats[g * 256 + 128 + c1] * (1.0f / NB) - m1 * m1;
  float is0 = 1.0f / sqrtf(v0 + 1e-5f);
  float is1 = 1.0f / sqrtf(v1 + 1e-5f);
  float ga0 = gamma[c0], ga1 = gamma[c1];
  float be0 = beta[c0], be1 = beta[c1];
  float w200 = W2[c0 * 2], w201 = W2[c0 * 2 + 1];
  float w210 = W2[c1 * 2], w211 = W2[c1 * 2 + 1];
  const float* z = zbase + (size_t)g * NB * DF;
  float* mmd = mmd_base + (size_t)g * NB * DF;
  int rbase = blockIdx.x * 16 + w * 4;
  for (int rr = 0; rr < 4; ++rr){
    int row = rbase + rr;
    float2 zv = *(const float2*)(z + (size_t)row * DF + c0);
    float y0 = fmaxf((zv.x - m0) * is0 * ga0 + be0, 0.f);
    float y1 = fmaxf((zv.y - m1) * is1 * ga1 + be1, 0.f);
    float2 yv; yv.x = y0; yv.y = y1;
    *(float2*)(mmd + (size_t)row * DF + c0) = yv;
    if (g == 0){
      float s0 = y0 * w200 + y1 * w210;
      float s1 = y0 * w201 + y1 * w211;
      for (int o = 32; o > 0; o >>= 1){
        s0 += __shfl_xor(s0, o);
        s1 += __shfl_xor(s1, o);
      }
      if (l == 0){
        hp[row * 2]     = s0 + b2[0];
        hp[row * 2 + 1] = s1 + b2[1];
      }
    }
  }
}

extern "C" __attribute__((used, visibility("default")))
void kernel_launch(void* const* d_in, const int* in_sizes, int n_in,
                   void* d_out, int out_size, void* d_ws, size_t ws_size,
                   hipStream_t stream){
  const float* h_in  = (const float*)d_in[0];
  const int* esrc = (const int*)d_in[1];
  const int* edst = (const int*)d_in[2];
  const int* x1   = (const int*)d_in[3];
  const int* x2   = (const int*)d_in[4];
  const int* x1t  = (const int*)d_in[5];
  const int* x2t  = (const int*)d_in[6];
  const float* Wself = (const float*)d_in[7];
  const float* Wneigh= (const float*)d_in[8];
  const float* bconv = (const float*)d_in[9];
  const float* W1    = (const float*)d_in[10];
  const float* b1    = (const float*)d_in[11];
  const float* gamma = (const float*)d_in[12];
  const float* beta  = (const float*)d_in[13];
  const float* W2    = (const float*)d_in[14];
  const float* b2    = (const float*)d_in[15];
  float* out = (float*)d_out;                   // fp32 outputs
  float* hp_out   = out;                        // [NB,2]
  float* mmd_base = out + 2 * NB;               // [2][NB,DF] contiguous

  // ---- workspace layout (~48.3 MB) ----
  float* zreg  = (float*)d_ws;                       // 2*NB*DF f32 (src|tar)
  unsigned short* aggb = (unsigned short*)zreg;      // alias (dead before z)
  float* stats = zreg + (size_t)2 * NB * DF;         // 512
  float* mstd  = stats + 512;                        // 512 (layout pad)
  float* dinv  = mstd + 512;                         // 50,048 (unused slot)
  int* cnt  = (int*)(dinv + 50048);                  // 50,000
  int* fill = cnt + NN;                              // 50,000
  int* rp   = fill + NN;                             // 50,016
  int* perm = rp + 50016;                            // 600,000
  int* bsum = perm + 600000;                         // 256
  int* cfill = bsum + 256;                           // 256 (196 used)
  unsigned short* h_c = (unsigned short*)(cfill + 256);   // NN*DF u16
  unsigned short* h1b = h_c + (size_t)NN * DF;            // NN*DF u16
  unsigned short* h2b = h_c;                 // alias: h_c dead after layer 0
  unsigned short* WsB = h1b + (size_t)NN * DF;  // 2*DF*DF u16 (both layers)
  unsigned short* WnB = WsB + 2 * DF * DF;      // 2*DF*DF u16
  unsigned short* W1B = WnB + 2 * DF * DF;      // 3*DF*DF u16
  unsigned int* tmp = (unsigned int*)(W1B + 3 * DF * DF); // NE u32 (pass A)
  (void)dinv;

  // fused prelude: h cast + zeroing + weight swizzle
  k_prelude<<<3710, 256, 0, stream>>>(h_in, h_c, Wself, Wneigh, W1,
                                      WsB, WnB, W1B, cnt, stats);

  // CSR build: hist -> scan -> two-pass counting-sort scatter (v2)
  k_hist<<<(NE + 255) / 256, 256, 0, stream>>>(edst, cnt);
  k_scan1<<<196, 256, 0, stream>>>(cnt, bsum);
  k_scan3<<<196, 256, 0, stream>>>(cnt, bsum, rp, cfill);
  k_scatA<<<SCA_B, 256, 0, stream>>>(esrc, edst, cfill, tmp);
  k_scatB<<<196, 256, 0, stream>>>(tmp, rp, fill, perm);

  // SAGE layer 0: h_c -> h1b
  k_agg<<<(NN + 3) / 4, 256, 0, stream>>>((const unsigned int*)h_c, rp, perm,
                                          (unsigned int*)aggb);
  k_layer_mfma<<<(NN + 127) / 128, 256, 0, stream>>>(h_c, aggb, WsB, WnB,
                                                     bconv, h1b);
  // SAGE layer 1: h1b -> h2b
  k_agg<<<(NN + 3) / 4, 256, 0, stream>>>((const unsigned int*)h1b, rp, perm,
                                          (unsigned int*)aggb);
  k_layer_mfma<<<(NN + 127) / 128, 256, 0, stream>>>(h1b, aggb, WsB + DF * DF,
                                                     WnB + DF * DF, bconv + DF,
                                                     h2b);

  // head: pair GEMM (+ fused col-stats), then normalize (+ fused h_p)
  k_pair_mfma<<<dim3(NB / 64, 2), 256, 0, stream>>>(h2b, x1, x2, x1t, x2t,
                                                    W1B, b1, zreg, stats);
  k_norm_hp<<<dim3(NB / 16, 2), 256, 0, stream>>>(zreg, stats, gamma, beta,
                                                  W2, b2, mmd_base, hp_out);
}

// Round 12
// 242.858 us; speedup vs baseline: 1.1770x; 1.1111x over previous
//
#include <hip/hip_runtime.h>

#define NN 50000   // nodes
#define NE 600000  // edges
#define DF 128     // features
#define NB 16384   // pair batch
#define SCA_B 256                 // pass-A blocks (1 per CU)
#define SCA_PER ((NE + SCA_B - 1) / SCA_B)   // 2344 edges/block
#define NBKT 196                  // coarse buckets (ceil(NN/256))
#define SCB_CAP 4352              // pass-B LDS edge capacity (23 sigma)

typedef short bf16x8 __attribute__((ext_vector_type(8)));
typedef float f32x4 __attribute__((ext_vector_type(4)));

__device__ __forceinline__ float bf2f(unsigned short u){
  return __uint_as_float(((unsigned int)u) << 16);
}
__device__ __forceinline__ unsigned short f2bf(float x){
  unsigned int b = __float_as_uint(x);
  return (unsigned short)((b + 0x7FFFu + ((b >> 16) & 1u)) >> 16);
}

// Original template symbol (defined, never launched).
__global__ void GraphSAGE_8504035246140_kernel(){ }

// ---- fused prelude: h cast | zero stats/chist | weight swizzle ----
// cnt/fill zeroing removed: per-node hist is gone (scatB derives rp).
__global__ __launch_bounds__(256) void k_prelude(
    const float* h_in, unsigned short* h_c,
    const float* Ws, const float* Wn, const float* W1,
    unsigned short* WsB, unsigned short* WnB, unsigned short* W1B,
    int* chist, float* stats){
  int b = blockIdx.x, t = threadIdx.x;
  if (b < 3125){                       // 3125*256 == NN*DF/8 exactly
    int i = b * 256 + t;
    const float4* s = (const float4*)h_in;
    float4 v0 = s[i * 2], v1 = s[i * 2 + 1];
    unsigned short d[8] = {f2bf(v0.x), f2bf(v0.y), f2bf(v0.z), f2bf(v0.w),
                           f2bf(v1.x), f2bf(v1.y), f2bf(v1.z), f2bf(v1.w)};
    *(bf16x8*)(h_c + i * 8) = *(bf16x8*)d;
  } else if (b < 3127){
    int i = (b - 3125) * 256 + t;
    if (i < 512) stats[i] = 0.f;
  } else if (b < 3128){
    if (t < NBKT) chist[t] = 0;
  } else {
    int idx = (b - 3128) * 256 + t;    // 192 blocks -> 49152 threads
    if (idx < 2 * DF * DF){
      int layer = idx >> 14;
      int e = idx & (DF * DF - 1);
      int k = e >> 7, n = e & 127;
      int dst = layer * DF * DF + (((k >> 3) * 128 + n) << 3) + (k & 7);
      WsB[dst] = f2bf(Ws[idx]);
      WnB[dst] = f2bf(Wn[idx]);
    }
    if (idx < 3 * DF * DF){
      int k = idx >> 7, n = idx & 127; // W1: 384x128
      W1B[(((k >> 3) * 128 + n) << 3) + (k & 7)] = f2bf(W1[idx]);
    }
  }
}

// ---- coarse histogram: 196 buckets of dst>>8, LDS-staged ----
__global__ __launch_bounds__(256) void k_chist(const int* dst, int* chist){
  __shared__ int h[NBKT];
  int t = threadIdx.x;
  if (t < NBKT) h[t] = 0;
  __syncthreads();
  int e0 = blockIdx.x * SCA_PER;
  int e1 = e0 + SCA_PER; if (e1 > NE) e1 = NE;
  for (int e = e0 + t; e < e1; e += 256) atomicAdd(&h[dst[e] >> 8], 1);
  __syncthreads();
  if (t < NBKT && h[t]) atomicAdd(&chist[t], h[t]);
}

// ---- coarse scan (1 block): bucket bases -> cfill (scatA cursors) + bbase --
__global__ __launch_bounds__(256) void k_cscan(
    const int* chist, int* cfill, int* bbase){
  __shared__ int sc[256];
  int t = threadIdx.x;
  int v = (t < NBKT) ? chist[t] : 0;
  sc[t] = v;
  __syncthreads();
  for (int o = 1; o < 256; o <<= 1){
    int x = (t >= o) ? sc[t - o] : 0;
    __syncthreads();
    sc[t] += x;
    __syncthreads();
  }
  if (t < NBKT){
    int base = sc[t] - v;
    cfill[t] = base;
    bbase[t] = base;
  }
  if (t == 0) bbase[NBKT] = NE;
}

// ---- scatter pass A: coarse bucket (dst>>8) chunk write (r11 winner) ----
__global__ __launch_bounds__(256) void k_scatA(
    const int* src, const int* dst, int* cfill, unsigned int* tmp){
  __shared__ unsigned int hist[NBKT];
  __shared__ unsigned int cursor[NBKT];
  int t = threadIdx.x;
  int e0 = blockIdx.x * SCA_PER;
  int e1 = e0 + SCA_PER; if (e1 > NE) e1 = NE;
  if (t < NBKT) hist[t] = 0;
  __syncthreads();
  for (int e = e0 + t; e < e1; e += 256) atomicAdd(&hist[dst[e] >> 8], 1u);
  __syncthreads();
  if (t < NBKT) cursor[t] = (unsigned int)atomicAdd(&cfill[t], (int)hist[t]);
  __syncthreads();
  for (int e = e0 + t; e < e1; e += 256){
    int d = dst[e];
    unsigned int off = atomicAdd(&cursor[d >> 8], 1u);
    tmp[off] = (unsigned int)src[e] | ((unsigned int)(d & 255) << 16);
  }
}

// ---- scatter pass B: per-bucket fine sort by dst&255 -> perm AND rp ------
// The bin-count exclusive scan IS rp[n]-bbase[b], so this kernel writes rp
// directly — the per-node global-atomic histogram + 2 scan kernels are gone.
// Overflow fallback (cap exceeded, ~23-sigma) places via LDS cursors.
__global__ __launch_bounds__(256) void k_scatB(
    const unsigned int* tmp, const int* bbase, int* rp, int* perm){
  __shared__ unsigned int hist[256];
  __shared__ unsigned int sc[256];
  __shared__ unsigned int ebuf[SCB_CAP];
  __shared__ unsigned int sbuf[SCB_CAP];
  int b = blockIdx.x, t = threadIdx.x;
  int n0 = b << 8;
  int s = bbase[b], e = bbase[b + 1];
  int cntb = e - s;
  bool fits = (cntb <= SCB_CAP);
  hist[t] = 0;
  __syncthreads();
  if (fits){
    for (int i = t; i < cntb; i += 256){
      unsigned int v = tmp[s + i];
      ebuf[i] = v;
      atomicAdd(&hist[(v >> 16) & 255], 1u);
    }
  } else {
    for (int i = t; i < cntb; i += 256)
      atomicAdd(&hist[(tmp[s + i] >> 16) & 255], 1u);
  }
  __syncthreads();
  unsigned int cntk = hist[t];
  sc[t] = cntk;
  __syncthreads();
  for (int o = 1; o < 256; o <<= 1){
    unsigned int x = (t >= o) ? sc[t - o] : 0;
    __syncthreads();
    sc[t] += x;
    __syncthreads();
  }
  unsigned int excl = sc[t] - cntk;
  int node = n0 + t;
  if (node < NN) rp[node] = s + (int)excl;
  if (b == NBKT - 1 && t == 0) rp[NN] = NE;
  hist[t] = excl;                       // reuse as placement cursor
  __syncthreads();
  if (fits){
    for (int i = t; i < cntb; i += 256){
      unsigned int v = ebuf[i];
      unsigned int off = atomicAdd(&hist[(v >> 16) & 255], 1u);
      sbuf[off] = v;
    }
    __syncthreads();
    for (int i = t; i < cntb; i += 256) perm[s + i] = (int)(sbuf[i] & 0xFFFFu);
  } else {
    for (int i = t; i < cntb; i += 256){
      unsigned int v = tmp[s + i];
      unsigned int off = atomicAdd(&hist[(v >> 16) & 255], 1u);
      perm[s + (int)off] = (int)(v & 0xFFFFu);
    }
  }
}

// ---- mean aggregation: one wave per node, uint4 gather, 16-edge batch ----
// (r5 structure: the measured best.) 16 lanes x 16B cover one 256B row ->
// 4 edge-rows per wave-load; tail is one predicated batch. Cross-slot
// combine via shfl_xor(16,32). di computed from row pointers.
__global__ __launch_bounds__(256) void k_agg(
    const unsigned int* hb32, const int* rp, const int* perm,
    unsigned int* agg32){
  int n = blockIdx.x * 4 + (threadIdx.x >> 6);
  if (n >= NN) return;
  int l = threadIdx.x & 63;
  int rs = l >> 4, li = l & 15;        // row slot 0..3, 16B chunk 0..15
  int s = rp[n], e = rp[n + 1];
  const unsigned int* hq = hb32 + li * 4;
  float a0 = 0.f, a1 = 0.f, a2 = 0.f, a3 = 0.f;
  float a4 = 0.f, a5 = 0.f, a6 = 0.f, a7 = 0.f;
  int i = s;
  for (; i + 16 <= e; i += 16){
    int p0 = perm[i + rs];
    int p1 = perm[i + 4 + rs];
    int p2 = perm[i + 8 + rs];
    int p3 = perm[i + 12 + rs];
    uint4 x0 = *(const uint4*)(hq + (size_t)p0 * 64);
    uint4 x1 = *(const uint4*)(hq + (size_t)p1 * 64);
    uint4 x2 = *(const uint4*)(hq + (size_t)p2 * 64);
    uint4 x3 = *(const uint4*)(hq + (size_t)p3 * 64);
    a0 += __uint_as_float(x0.x << 16); a1 += __uint_as_float(x0.x & 0xffff0000u);
    a2 += __uint_as_float(x0.y << 16); a3 += __uint_as_float(x0.y & 0xffff0000u);
    a4 += __uint_as_float(x0.z << 16); a5 += __uint_as_float(x0.z & 0xffff0000u);
    a6 += __uint_as_float(x0.w << 16); a7 += __uint_as_float(x0.w & 0xffff0000u);
    a0 += __uint_as_float(x1.x << 16); a1 += __uint_as_float(x1.x & 0xffff0000u);
    a2 += __uint_as_float(x1.y << 16); a3 += __uint_as_float(x1.y & 0xffff0000u);
    a4 += __uint_as_float(x1.z << 16); a5 += __uint_as_float(x1.z & 0xffff0000u);
    a6 += __uint_as_float(x1.w << 16); a7 += __uint_as_float(x1.w & 0xffff0000u);
    a0 += __uint_as_float(x2.x << 16); a1 += __uint_as_float(x2.x & 0xffff0000u);
    a2 += __uint_as_float(x2.y << 16); a3 += __uint_as_float(x2.y & 0xffff0000u);
    a4 += __uint_as_float(x2.z << 16); a5 += __uint_as_float(x2.z & 0xffff0000u);
    a6 += __uint_as_float(x2.w << 16); a7 += __uint_as_float(x2.w & 0xffff0000u);
    a0 += __uint_as_float(x3.x << 16); a1 += __uint_as_float(x3.x & 0xffff0000u);
    a2 += __uint_as_float(x3.y << 16); a3 += __uint_as_float(x3.y & 0xffff0000u);
    a4 += __uint_as_float(x3.z << 16); a5 += __uint_as_float(x3.z & 0xffff0000u);
    a6 += __uint_as_float(x3.w << 16); a7 += __uint_as_float(x3.w & 0xffff0000u);
  }
  if (i < e){
    int i0 = i + rs, i1 = i + 4 + rs, i2 = i + 8 + rs, i3 = i + 12 + rs;
    int p0 = perm[i0 < e ? i0 : s];
    int p1 = perm[i1 < e ? i1 : s];
    int p2 = perm[i2 < e ? i2 : s];
    int p3 = perm[i3 < e ? i3 : s];
    uint4 x0 = *(const uint4*)(hq + (size_t)p0 * 64);
    uint4 x1 = *(const uint4*)(hq + (size_t)p1 * 64);
    uint4 x2 = *(const uint4*)(hq + (size_t)p2 * 64);
    uint4 x3 = *(const uint4*)(hq + (size_t)p3 * 64);
    if (i0 < e){
      a0 += __uint_as_float(x0.x << 16); a1 += __uint_as_float(x0.x & 0xffff0000u);
      a2 += __uint_as_float(x0.y << 16); a3 += __uint_as_float(x0.y & 0xffff0000u);
      a4 += __uint_as_float(x0.z << 16); a5 += __uint_as_float(x0.z & 0xffff0000u);
      a6 += __uint_as_float(x0.w << 16); a7 += __uint_as_float(x0.w & 0xffff0000u);
    }
    if (i1 < e){
      a0 += __uint_as_float(x1.x << 16); a1 += __uint_as_float(x1.x & 0xffff0000u);
      a2 += __uint_as_float(x1.y << 16); a3 += __uint_as_float(x1.y & 0xffff0000u);
      a4 += __uint_as_float(x1.z << 16); a5 += __uint_as_float(x1.z & 0xffff0000u);
      a6 += __uint_as_float(x1.w << 16); a7 += __uint_as_float(x1.w & 0xffff0000u);
    }
    if (i2 < e){
      a0 += __uint_as_float(x2.x << 16); a1 += __uint_as_float(x2.x & 0xffff0000u);
      a2 += __uint_as_float(x2.y << 16); a3 += __uint_as_float(x2.y & 0xffff0000u);
      a4 += __uint_as_float(x2.z << 16); a5 += __uint_as_float(x2.z & 0xffff0000u);
      a6 += __uint_as_float(x2.w << 16); a7 += __uint_as_float(x2.w & 0xffff0000u);
    }
    if (i3 < e){
      a0 += __uint_as_float(x3.x << 16); a1 += __uint_as_float(x3.x & 0xffff0000u);
      a2 += __uint_as_float(x3.y << 16); a3 += __uint_as_float(x3.y & 0xffff0000u);
      a4 += __uint_as_float(x3.z << 16); a5 += __uint_as_float(x3.z & 0xffff0000u);
      a6 += __uint_as_float(x3.w << 16); a7 += __uint_as_float(x3.w & 0xffff0000u);
    }
  }
  a0 += __shfl_xor(a0, 16); a1 += __shfl_xor(a1, 16);
  a2 += __shfl_xor(a2, 16); a3 += __shfl_xor(a3, 16);
  a4 += __shfl_xor(a4, 16); a5 += __shfl_xor(a5, 16);
  a6 += __shfl_xor(a6, 16); a7 += __shfl_xor(a7, 16);
  a0 += __shfl_xor(a0, 32); a1 += __shfl_xor(a1, 32);
  a2 += __shfl_xor(a2, 32); a3 += __shfl_xor(a3, 32);
  a4 += __shfl_xor(a4, 32); a5 += __shfl_xor(a5, 32);
  a6 += __shfl_xor(a6, 32); a7 += __shfl_xor(a7, 32);
  if (rs == 0){
    float di = 1.0f / fmaxf((float)(e - s), 1.0f);
    uint4 r;
    r.x = (unsigned int)f2bf(a0 * di) | ((unsigned int)f2bf(a1 * di) << 16);
    r.y = (unsigned int)f2bf(a2 * di) | ((unsigned int)f2bf(a3 * di) << 16);
    r.z = (unsigned int)f2bf(a4 * di) | ((unsigned int)f2bf(a5 * di) << 16);
    r.w = (unsigned int)f2bf(a6 * di) | ((unsigned int)f2bf(a7 * di) << 16);
    *(uint4*)(agg32 + (size_t)n * 64 + li * 4) = r;
  }
}

// ---- layer GEMM via MFMA, 2 row-tiles per wave (r8 winner) ----
__global__ __launch_bounds__(256) void k_layer_mfma(
    const unsigned short* hb, const unsigned short* aggb,
    const unsigned short* WsB, const unsigned short* WnB,
    const float* bias, unsigned short* hout){
  int t = threadIdx.x;
  int w = t >> 6, l = t & 63;
  int m = l & 15, q = l >> 4;
  int r0 = blockIdx.x * 128 + w * 16;          // tile0 base; tile1 = +64
  int arow0 = r0 + m;       if (arow0 > NN - 1) arow0 = NN - 1;
  int arow1 = r0 + 64 + m;  if (arow1 > NN - 1) arow1 = NN - 1;
  const unsigned short* hp0 = hb   + (size_t)arow0 * DF + q * 8;
  const unsigned short* ap0 = aggb + (size_t)arow0 * DF + q * 8;
  const unsigned short* hp1 = hb   + (size_t)arow1 * DF + q * 8;
  const unsigned short* ap1 = aggb + (size_t)arow1 * DF + q * 8;
  f32x4 acc0[8], acc1[8];
  for (int ct = 0; ct < 8; ++ct){
    float bbc = bias[ct * 16 + m];
    acc0[ct] = (f32x4){bbc, bbc, bbc, bbc};
    acc1[ct] = (f32x4){bbc, bbc, bbc, bbc};
  }
  for (int kt = 0; kt < 4; ++kt){
    bf16x8 a_h0 = *(const bf16x8*)(hp0 + kt * 32);
    bf16x8 a_g0 = *(const bf16x8*)(ap0 + kt * 32);
    bf16x8 a_h1 = *(const bf16x8*)(hp1 + kt * 32);
    bf16x8 a_g1 = *(const bf16x8*)(ap1 + kt * 32);
    int kg = kt * 4 + q;
    for (int ct = 0; ct < 8; ++ct){
      bf16x8 b_s = *(const bf16x8*)(WsB + (((kg << 7) + ct * 16 + m) << 3));
      bf16x8 b_n = *(const bf16x8*)(WnB + (((kg << 7) + ct * 16 + m) << 3));
      acc0[ct] = __builtin_amdgcn_mfma_f32_16x16x32_bf16(a_h0, b_s, acc0[ct], 0, 0, 0);
      acc0[ct] = __builtin_amdgcn_mfma_f32_16x16x32_bf16(a_g0, b_n, acc0[ct], 0, 0, 0);
      acc1[ct] = __builtin_amdgcn_mfma_f32_16x16x32_bf16(a_h1, b_s, acc1[ct], 0, 0, 0);
      acc1[ct] = __builtin_amdgcn_mfma_f32_16x16x32_bf16(a_g1, b_n, acc1[ct], 0, 0, 0);
    }
  }
  for (int ct = 0; ct < 8; ++ct){
    int col = ct * 16 + m;
    for (int reg = 0; reg < 4; ++reg){
      int row0 = r0 + q * 4 + reg;
      int row1 = row0 + 64;
      if (row0 < NN) hout[(size_t)row0 * DF + col] = f2bf(fmaxf(acc0[ct][reg], 0.f));
      if (row1 < NN) hout[(size_t)row1 * DF + col] = f2bf(fmaxf(acc1[ct][reg], 0.f));
    }
  }
}

// ---- pair GEMM via MFMA + fused BN column stats; src/tar via blockIdx.y ----
__global__ __launch_bounds__(256) void k_pair_mfma(
    const unsigned short* h2,
    const int* x1, const int* x2, const int* x1t, const int* x2t,
    const unsigned short* W1B, const float* b1, float* zbase, float* stats){
  __shared__ __align__(16) unsigned short F[64 * 392];
  __shared__ float csum[128], csq[128];
  int g = blockIdx.y;
  const int* ia = g ? x1t : x1;
  const int* ib = g ? x2t : x2;
  float* z = zbase + (size_t)g * NB * DF;
  int t = threadIdx.x;
  if (t < 128){ csum[t] = 0.f; csq[t] = 0.f; }
  int r0 = blockIdx.x * 64;
  int i = t >> 2, qq = t & 3;
  int r = r0 + i;
  int a = ia[r], b = ib[r];
  const unsigned short* pa = h2 + (size_t)a * DF + qq * 32;
  const unsigned short* pb = h2 + (size_t)b * DF + qq * 32;
  unsigned short* fr = F + i * 392;
  for (int jj = 0; jj < 4; ++jj){
    bf16x8 va = *(const bf16x8*)(pa + jj * 8);
    bf16x8 vb = *(const bf16x8*)(pb + jj * 8);
    *(bf16x8*)(fr + qq * 32 + jj * 8) = va;
    *(bf16x8*)(fr + 128 + qq * 32 + jj * 8) = vb;
    unsigned short d[8];
    for (int e = 0; e < 8; ++e){
      float fa = bf2f((unsigned short)va[e]);
      float fb = bf2f((unsigned short)vb[e]);
      d[e] = f2bf(fabsf(fa - fb));
    }
    *(bf16x8*)(fr + 256 + qq * 32 + jj * 8) = *(bf16x8*)d;
  }
  __syncthreads();
  int w = t >> 6, l = t & 63;
  int m = l & 15, q = l >> 4;
  int rl = w * 16 + m;
  f32x4 acc[8];
  for (int ct = 0; ct < 8; ++ct){
    float bbc = b1[ct * 16 + m];
    acc[ct] = (f32x4){bbc, bbc, bbc, bbc};
  }
  for (int kt = 0; kt < 12; ++kt){
    bf16x8 af = *(const bf16x8*)(F + rl * 392 + kt * 32 + q * 8);
    int kg = kt * 4 + q;
    for (int ct = 0; ct < 8; ++ct){
      bf16x8 bfr = *(const bf16x8*)(W1B + (((kg << 7) + ct * 16 + m) << 3));
      acc[ct] = __builtin_amdgcn_mfma_f32_16x16x32_bf16(af, bfr, acc[ct], 0, 0, 0);
    }
  }
  for (int ct = 0; ct < 8; ++ct){
    int col = ct * 16 + m;
    int row = r0 + w * 16 + q * 4;
    float s = 0.f, s2 = 0.f;
    for (int reg = 0; reg < 4; ++reg){
      float v = acc[ct][reg];
      z[(size_t)(row + reg) * DF + col] = v;
      s += v; s2 += v * v;
    }
    atomicAdd(&csum[col], s);
    atomicAdd(&csq[col], s2);
  }
  __syncthreads();
  if (t < 128){
    atomicAdd(&stats[g * 256 + t], csum[t]);
    atomicAdd(&stats[g * 256 + 128 + t], csq[t]);
  }
}

// ---- fused BN-normalize + relu + (src only) h_p GEMM, barrier-free ----
__global__ __launch_bounds__(256) void k_norm_hp(
    const float* zbase, const float* stats,
    const float* gamma, const float* beta,
    const float* W2, const float* b2, float* mmd_base, float* hp){
  int g = blockIdx.y;
  int t = threadIdx.x;
  int w = t >> 6, l = t & 63;
  int c0 = l * 2, c1 = c0 + 1;
  float m0 = stats[g * 256 + c0] * (1.0f / NB);
  float m1 = stats[g * 256 + c1] * (1.0f / NB);
  float v0 = stats[g * 256 + 128 + c0] * (1.0f / NB) - m0 * m0;
  float v1 = stats[g * 256 + 128 + c1] * (1.0f / NB) - m1 * m1;
  float is0 = 1.0f / sqrtf(v0 + 1e-5f);
  float is1 = 1.0f / sqrtf(v1 + 1e-5f);
  float ga0 = gamma[c0], ga1 = gamma[c1];
  float be0 = beta[c0], be1 = beta[c1];
  float w200 = W2[c0 * 2], w201 = W2[c0 * 2 + 1];
  float w210 = W2[c1 * 2], w211 = W2[c1 * 2 + 1];
  const float* z = zbase + (size_t)g * NB * DF;
  float* mmd = mmd_base + (size_t)g * NB * DF;
  int rbase = blockIdx.x * 16 + w * 4;
  for (int rr = 0; rr < 4; ++rr){
    int row = rbase + rr;
    float2 zv = *(const float2*)(z + (size_t)row * DF + c0);
    float y0 = fmaxf((zv.x - m0) * is0 * ga0 + be0, 0.f);
    float y1 = fmaxf((zv.y - m1) * is1 * ga1 + be1, 0.f);
    float2 yv; yv.x = y0; yv.y = y1;
    *(float2*)(mmd + (size_t)row * DF + c0) = yv;
    if (g == 0){
      float s0 = y0 * w200 + y1 * w210;
      float s1 = y0 * w201 + y1 * w211;
      for (int o = 32; o > 0; o >>= 1){
        s0 += __shfl_xor(s0, o);
        s1 += __shfl_xor(s1, o);
      }
      if (l == 0){
        hp[row * 2]     = s0 + b2[0];
        hp[row * 2 + 1] = s1 + b2[1];
      }
    }
  }
}

extern "C" __attribute__((used, visibility("default")))
void kernel_launch(void* const* d_in, const int* in_sizes, int n_in,
                   void* d_out, int out_size, void* d_ws, size_t ws_size,
                   hipStream_t stream){
  const float* h_in  = (const float*)d_in[0];
  const int* esrc = (const int*)d_in[1];
  const int* edst = (const int*)d_in[2];
  const int* x1   = (const int*)d_in[3];
  const int* x2   = (const int*)d_in[4];
  const int* x1t  = (const int*)d_in[5];
  const int* x2t  = (const int*)d_in[6];
  const float* Wself = (const float*)d_in[7];
  const float* Wneigh= (const float*)d_in[8];
  const float* bconv = (const float*)d_in[9];
  const float* W1    = (const float*)d_in[10];
  const float* b1    = (const float*)d_in[11];
  const float* gamma = (const float*)d_in[12];
  const float* beta  = (const float*)d_in[13];
  const float* W2    = (const float*)d_in[14];
  const float* b2    = (const float*)d_in[15];
  float* out = (float*)d_out;                   // fp32 outputs
  float* hp_out   = out;                        // [NB,2]
  float* mmd_base = out + 2 * NB;               // [2][NB,DF] contiguous

  // ---- workspace layout (~48.3 MB) ----
  float* zreg  = (float*)d_ws;                       // 2*NB*DF f32 (src|tar)
  unsigned short* aggb = (unsigned short*)zreg;      // alias (dead before z)
  float* stats = zreg + (size_t)2 * NB * DF;         // 512
  float* mstd  = stats + 512;                        // 512 (layout pad)
  float* dinv  = mstd + 512;                         // 50,048 (unused slot)
  int* bbase = (int*)(dinv + 50048);                 // 197 (in old cnt slot)
  int* chist = bbase + 256;                          // 196
  int* rp   = chist + 256;                           // 50,016
  int* perm = rp + 50016;                            // 600,000
  int* bsum = perm + 600000;                         // 256 (unused slot)
  int* cfill = bsum + 256;                           // 256 (196 used)
  unsigned short* h_c = (unsigned short*)(cfill + 256);   // NN*DF u16
  unsigned short* h1b = h_c + (size_t)NN * DF;            // NN*DF u16
  unsigned short* h2b = h_c;                 // alias: h_c dead after layer 0
  unsigned short* WsB = h1b + (size_t)NN * DF;  // 2*DF*DF u16 (both layers)
  unsigned short* WnB = WsB + 2 * DF * DF;      // 2*DF*DF u16
  unsigned short* W1B = WnB + 2 * DF * DF;      // 3*DF*DF u16
  unsigned int* tmp = (unsigned int*)(W1B + 3 * DF * DF); // NE u32 (pass A)
  (void)dinv; (void)bsum;

  // fused prelude: h cast + stats/chist zero + weight swizzle
  k_prelude<<<3320, 256, 0, stream>>>(h_in, h_c, Wself, Wneigh, W1,
                                      WsB, WnB, W1B, chist, stats);

  // CSR build: coarse hist -> coarse scan -> scatA -> scatB (writes rp+perm)
  k_chist<<<SCA_B, 256, 0, stream>>>(edst, chist);
  k_cscan<<<1, 256, 0, stream>>>(chist, cfill, bbase);
  k_scatA<<<SCA_B, 256, 0, stream>>>(esrc, edst, cfill, tmp);
  k_scatB<<<NBKT, 256, 0, stream>>>(tmp, bbase, rp, perm);

  // SAGE layer 0: h_c -> h1b
  k_agg<<<(NN + 3) / 4, 256, 0, stream>>>((const unsigned int*)h_c, rp, perm,
                                          (unsigned int*)aggb);
  k_layer_mfma<<<(NN + 127) / 128, 256, 0, stream>>>(h_c, aggb, WsB, WnB,
                                                     bconv, h1b);
  // SAGE layer 1: h1b -> h2b
  k_agg<<<(NN + 3) / 4, 256, 0, stream>>>((const unsigned int*)h1b, rp, perm,
                                          (unsigned int*)aggb);
  k_layer_mfma<<<(NN + 127) / 128, 256, 0, stream>>>(h1b, aggb, WsB + DF * DF,
                                                     WnB + DF * DF, bconv + DF,
                                                     h2b);

  // head: pair GEMM (+ fused col-stats), then normalize (+ fused h_p)
  k_pair_mfma<<<dim3(NB / 64, 2), 256, 0, stream>>>(h2b, x1, x2, x1t, x2t,
                                                    W1B, b1, zreg, stats);
  k_norm_hp<<<dim3(NB / 16, 2), 256, 0, stream>>>(zreg, stats, gamma, beta,
                                                  W2, b2, mmd_base, hp_out);
}